// Round 6
// baseline (516.153 us; speedup 1.0000x reference)
//
#include <hip/hip_runtime.h>
#include <hip/hip_bf16.h>
#include <stdint.h>
#include <math.h>

// DIM=512, B=16, L=2048, MLP_RATIO=4, GATE_HID=128
#define DIMC 512
#define SEQ  2048
#define NB   16
#define MTOT (NB * SEQ)          // 32768 tokens
#define HID  2048

// All fp8 GEMM-operand buffers are stored XOR-swizzled in global memory:
//   buf[row][c ^ SWZ(row)] = true[row][c]
// 8B-granule swizzle, bijective in row&15:
//   SWZ(row) = ((row&7)<<4) | (row&8)
// global_load_lds staging stays identity (raw row copy, m97-proven); the GEMM
// fragment reader unswizzles with pcol = kcol ^ SWZ(cn) (fragment rows satisfy
// row&15 == cn). Each 16-lane MFMA group hits 16 distinct 8B slots = all 32
// banks once -> ds_read_b64 conflict-free (verified: SQ_LDS_BANK_CONFLICT
// 4.19M -> 0). XOR touches bits 3-6 only: every write (2B/4B aligned) stays in
// its 8B slot, every slot stays in its 128B window.
#define SWZ(row) ((((row) & 7) << 4) | ((row) & 8))

typedef float v4f __attribute__((ext_vector_type(4)));

__device__ __forceinline__ float bf2f(unsigned short u) {
  union { unsigned int i; float f; } v; v.i = ((unsigned int)u) << 16; return v.f;
}
__device__ __forceinline__ unsigned short f2bf(float f) {
  union { float f; unsigned int i; } v; v.f = f;
  unsigned int r = v.i + 0x7fffu + ((v.i >> 16) & 1u);  // RNE
  return (unsigned short)(r >> 16);
}
// Exact gelu (erf) — used only where output stays fp32 (gate path).
__device__ __forceinline__ float gelu_f(float v) {
  return 0.5f * v * (1.f + erff(v * 0.70710678118654752440f));
}
// Fast gelu: sigmoid form v*sigma(1.702v) — 5 VALU ops (mul,exp,add,rcp,mul).
// |err| < ~0.02 pre-quantization, absorbed by fp8 e4m3 consumers (ulp ~6%)
// and the 1e-4 layer-scales on both residual paths (R2's gelu swap left
// absmax bit-identical). Overflow-safe: exp -> 0/inf, never NaN.
__device__ __forceinline__ float gelu_fast(float v) {
  float e = __expf(v * -1.702f);
  return v * __builtin_amdgcn_rcpf(1.f + e);
}
// pack fp32 -> fp8 e4m3 (OCP)
__device__ __forceinline__ unsigned short pk_fp8(float a, float b) {
  return (unsigned short)__builtin_amdgcn_cvt_pk_fp8_f32(a, b, 0, false);
}
__device__ __forceinline__ unsigned int pk_fp8x4(float a, float b, float c, float d) {
  int lo = __builtin_amdgcn_cvt_pk_fp8_f32(a, b, 0, false);
  return (unsigned int)__builtin_amdgcn_cvt_pk_fp8_f32(c, d, lo, true);
}

typedef __attribute__((address_space(1))) const void cglobal_void;
typedef __attribute__((address_space(3))) void lds_void;
__device__ __forceinline__ void load16_lds(const void* g, void* l) {
  __builtin_amdgcn_global_load_lds((cglobal_void*)g, (lds_void*)l, 16, 0, 0);
}

// ---------------------------------------------------------------------------
// Fused weight pack: all four weights fp32 -> fp8 e4m3 (swizzled dest) in one
// launch; also zeroes gsum. Pair index p covers: [0,131072) wmix;
// [131072,262144) wout^T; [262144,786432) ffn_w1^T; [786432,1310720) ffn_w2^T.
// ---------------------------------------------------------------------------
__global__ __launch_bounds__(256) void pack_all(
    const float* __restrict__ wmix, const float* __restrict__ wout,
    const float* __restrict__ ffn_w1, const float* __restrict__ ffn_w2,
    unsigned char* __restrict__ wmix8, unsigned char* __restrict__ wout8,
    unsigned char* __restrict__ w18, unsigned char* __restrict__ w28,
    float* __restrict__ gsum) {
  int p = blockIdx.x * 256 + threadIdx.x;
  if (p < NB * DIMC) gsum[p] = 0.f;

  const float* in; unsigned char* out; int R, C, trans;
  if (p < 131072)      { in = wmix;   out = wmix8; R = 512;  C = 512;  trans = 0; }
  else if (p < 262144) { in = wout;   out = wout8; R = 512;  C = 512;  trans = 1; p -= 131072; }
  else if (p < 786432) { in = ffn_w1; out = w18;   R = 2048; C = 512;  trans = 1; p -= 262144; }
  else                 { in = ffn_w2; out = w28;   R = 512;  C = 2048; trans = 1; p -= 786432; }
  int r = (p * 2) / C, c = (p * 2) - r * C;
  float v0, v1;
  if (trans) { v0 = in[(size_t)c * R + r]; v1 = in[(size_t)(c + 1) * R + r]; }
  else       { v0 = in[(size_t)r * C + c]; v1 = in[(size_t)r * C + c + 1]; }
  *(unsigned short*)(out + (size_t)r * C + (c ^ SWZ(r))) = pk_fp8(v0, v1);
}

// ---------------------------------------------------------------------------
// LN1 + (dwconv3+5+7)/3 + GELU -> g fp8 [M,512] (swizzled); accumulates gsum.
// ---------------------------------------------------------------------------
__global__ __launch_bounds__(256) void ln1_conv(
    const float* __restrict__ x, const float* __restrict__ lg, const float* __restrict__ lb,
    const float* __restrict__ w3, const float* __restrict__ b3,
    const float* __restrict__ w5, const float* __restrict__ b5,
    const float* __restrict__ w7, const float* __restrict__ b7,
    unsigned char* __restrict__ gout, float* __restrict__ gsum) {
  __shared__ __align__(16) unsigned short ht[38 * DIMC];
  int blk = blockIdx.x;
  int b = blk >> 6;
  int l0 = (blk & 63) << 5;
  int tid = threadIdx.x, lane = tid & 63, w = tid >> 6;

  for (int r = w; r < 38; r += 4) {
    int l = l0 - 3 + r;
    unsigned short* hrow = ht + r * DIMC;
    if (l < 0 || l >= SEQ) {
      ushort4 z; z.x = z.y = z.z = z.w = 0;
      *(ushort4*)&hrow[lane * 4] = z;
      *(ushort4*)&hrow[256 + lane * 4] = z;
    } else {
      const float4* xp = (const float4*)(x + ((size_t)(b * SEQ + l)) * DIMC);
      float4 v0 = xp[lane], v1 = xp[lane + 64];
      float s = v0.x + v0.y + v0.z + v0.w + v1.x + v1.y + v1.z + v1.w;
      float q = v0.x * v0.x + v0.y * v0.y + v0.z * v0.z + v0.w * v0.w +
                v1.x * v1.x + v1.y * v1.y + v1.z * v1.z + v1.w * v1.w;
#pragma unroll
      for (int o = 32; o > 0; o >>= 1) { s += __shfl_xor(s, o); q += __shfl_xor(q, o); }
      float mu = s * (1.f / 512.f);
      float rs = rsqrtf(q * (1.f / 512.f) - mu * mu + 1e-5f);
      float4 ga = ((const float4*)lg)[lane], gb = ((const float4*)lg)[lane + 64];
      float4 ba = ((const float4*)lb)[lane], bb = ((const float4*)lb)[lane + 64];
      ushort4 o0, o1;
      o0.x = f2bf((v0.x - mu) * rs * ga.x + ba.x);
      o0.y = f2bf((v0.y - mu) * rs * ga.y + ba.y);
      o0.z = f2bf((v0.z - mu) * rs * ga.z + ba.z);
      o0.w = f2bf((v0.w - mu) * rs * ga.w + ba.w);
      o1.x = f2bf((v1.x - mu) * rs * gb.x + bb.x);
      o1.y = f2bf((v1.y - mu) * rs * gb.y + bb.y);
      o1.z = f2bf((v1.z - mu) * rs * gb.z + bb.z);
      o1.w = f2bf((v1.w - mu) * rs * gb.w + bb.w);
      *(ushort4*)&hrow[lane * 4] = o0;
      *(ushort4*)&hrow[256 + lane * 4] = o1;
    }
  }
  __syncthreads();

  int d0 = tid << 1;
  float t3[2][3], t5[2][5], t7[2][7], cb[2];
#pragma unroll
  for (int j = 0; j < 2; j++) {
    int d = d0 + j;
    cb[j] = b3[d] + b5[d] + b7[d];
#pragma unroll
    for (int t = 0; t < 3; t++) t3[j][t] = w3[d * 3 + t];
#pragma unroll
    for (int t = 0; t < 5; t++) t5[j][t] = w5[d * 5 + t];
#pragma unroll
    for (int t = 0; t < 7; t++) t7[j][t] = w7[d * 7 + t];
  }
  float sum0 = 0.f, sum1 = 0.f;
  size_t rbase = ((size_t)(b * SEQ + l0)) * DIMC;
  for (int l = 0; l < 32; l++) {
    float h0[7], h1[7];
#pragma unroll
    for (int r = 0; r < 7; r++) {
      unsigned int pk = *(const unsigned int*)&ht[(l + r) * DIMC + d0];
      h0[r] = bf2f((unsigned short)pk);
      h1[r] = bf2f((unsigned short)(pk >> 16));
    }
    float a0 = cb[0], a1 = cb[1];
#pragma unroll
    for (int t = 0; t < 7; t++) { a0 += t7[0][t] * h0[t];     a1 += t7[1][t] * h1[t]; }
#pragma unroll
    for (int t = 0; t < 5; t++) { a0 += t5[0][t] * h0[t + 1]; a1 += t5[1][t] * h1[t + 1]; }
#pragma unroll
    for (int t = 0; t < 3; t++) { a0 += t3[0][t] * h0[t + 2]; a1 += t3[1][t] * h1[t + 2]; }
    a0 *= (1.f / 3.f); a1 *= (1.f / 3.f);
    float g0 = gelu_fast(a0), g1 = gelu_fast(a1);
    // row = b*SEQ + l0 + l; row&15 == l&15 (l0 multiple of 32)
    *(unsigned short*)(gout + rbase + (size_t)l * DIMC + (d0 ^ SWZ(l))) = pk_fp8(g0, g1);
    sum0 += g0; sum1 += g1;
  }
  atomicAdd(&gsum[b * DIMC + d0], sum0);
  atomicAdd(&gsum[b * DIMC + d0 + 1], sum1);
}

// ---------------------------------------------------------------------------
// Gate (exact fp32): ct = (gsum/L)@wmix^T + bmix; gate = sig(gelu(ct@w1+b1)@w2+b2)
// ---------------------------------------------------------------------------
__global__ __launch_bounds__(1024) void gate_kernel(
    const float* __restrict__ gsum, const float* __restrict__ wmix, const float* __restrict__ bmix,
    const float* __restrict__ cg_w1, const float* __restrict__ cg_b1,
    const float* __restrict__ cg_w2, const float* __restrict__ cg_b2,
    float* __restrict__ gate) {
  __shared__ float gbar[512];
  __shared__ float ct[512];
  __shared__ float part2[8][128];
  __shared__ float t1[128];
  __shared__ float part3[2][512];
  int b = blockIdx.x, tid = threadIdx.x;
  int lane = tid & 63, w = tid >> 6;   // 16 waves

  if (tid < 512) gbar[tid] = gsum[b * 512 + tid] * (1.f / (float)SEQ);
  __syncthreads();

  // Phase 1: ct[o] = gbar . wmix[o,:] + bmix[o].
  {
    const float4* gb4 = (const float4*)gbar;
    float4 g0 = gb4[lane * 2], g1 = gb4[lane * 2 + 1];
#pragma unroll 4
    for (int i = 0; i < 32; i++) {
      int o = w * 32 + i;
      const float4* wr = (const float4*)(wmix + (size_t)o * 512);
      float4 a0 = wr[lane * 2], a1 = wr[lane * 2 + 1];
      float s = a0.x * g0.x + a0.y * g0.y + a0.z * g0.z + a0.w * g0.w +
                a1.x * g1.x + a1.y * g1.y + a1.z * g1.z + a1.w * g1.w;
#pragma unroll
      for (int off = 32; off > 0; off >>= 1) s += __shfl_xor(s, off);
      if (lane == 0) ct[o] = s + bmix[o];
    }
  }
  __syncthreads();

  // Phase 2: t1[h] = gelu(ct . cg_w1[:,h] + cg_b1[h]).
  {
    int h = tid & 127, g = tid >> 7;
    float s = 0.f;
    const float* wp = cg_w1 + (size_t)(g * 64) * 128 + h;
#pragma unroll 8
    for (int c = 0; c < 64; c++) s += ct[g * 64 + c] * wp[c * 128];
    part2[g][h] = s;
  }
  __syncthreads();
  if (tid < 128) {
    float s = cg_b1[tid];
#pragma unroll
    for (int g = 0; g < 8; g++) s += part2[g][tid];
    t1[tid] = gelu_f(s);
  }
  __syncthreads();

  // Phase 3: gate[o] = sigmoid(t1 . cg_w2[:,o] + cg_b2[o]).
  {
    int o = tid & 511, g = tid >> 9;
    float s = 0.f;
    const float* wp = cg_w2 + (size_t)(g * 64) * 512 + o;
#pragma unroll 8
    for (int h = 0; h < 64; h++) s += t1[g * 64 + h] * wp[h * 512];
    part3[g][o] = s;
  }
  __syncthreads();
  if (tid < 512) {
    float s = cg_b2[tid] + part3[0][tid] + part3[1][tid];
    gate[b * 512 + tid] = 1.f / (1.f + expf(-s));
  }
}

// ---------------------------------------------------------------------------
// LN2: h2 = LN(y) fp8 (swizzled). One wave per token.
// ---------------------------------------------------------------------------
__global__ __launch_bounds__(256) void ln2_kernel(
    const float* __restrict__ y, const float* __restrict__ lg, const float* __restrict__ lb,
    unsigned char* __restrict__ h2) {
  int tok = (blockIdx.x << 2) + (threadIdx.x >> 6);
  int lane = threadIdx.x & 63;
  const float4* yp = (const float4*)(y + ((size_t)tok) * DIMC);
  float4 v0 = yp[lane], v1 = yp[lane + 64];
  float s = v0.x + v0.y + v0.z + v0.w + v1.x + v1.y + v1.z + v1.w;
  float q = v0.x * v0.x + v0.y * v0.y + v0.z * v0.z + v0.w * v0.w +
            v1.x * v1.x + v1.y * v1.y + v1.z * v1.z + v1.w * v1.w;
#pragma unroll
  for (int o = 32; o > 0; o >>= 1) { s += __shfl_xor(s, o); q += __shfl_xor(q, o); }
  float mu = s * (1.f / 512.f);
  float rs = rsqrtf(q * (1.f / 512.f) - mu * mu + 1e-5f);
  float4 ga = ((const float4*)lg)[lane], gb = ((const float4*)lg)[lane + 64];
  float4 ba = ((const float4*)lb)[lane], bb = ((const float4*)lb)[lane + 64];
  unsigned char* hp = h2 + (size_t)tok * DIMC;
  int sw = SWZ(tok);
  *(unsigned int*)(hp + ((lane * 4) ^ sw)) = pk_fp8x4(
      (v0.x - mu) * rs * ga.x + ba.x, (v0.y - mu) * rs * ga.y + ba.y,
      (v0.z - mu) * rs * ga.z + ba.z, (v0.w - mu) * rs * ga.w + ba.w);
  *(unsigned int*)(hp + (256 + ((lane * 4) ^ sw))) = pk_fp8x4(
      (v1.x - mu) * rs * gb.x + bb.x, (v1.y - mu) * rs * gb.y + bb.y,
      (v1.z - mu) * rs * gb.z + bb.z, (v1.w - mu) * rs * gb.w + bb.w);
}

// ---------------------------------------------------------------------------
// fp8 GEMM, C = A @ B^T (+epilogue). A [M,lda], B [N,ldb] fp8, K-major,
// both stored XOR-swizzled (SWZ). 128x128 tile, BK=128, 4 waves x 4x4
// mfma_f32_16x16x32_fp8_fp8. Staging = identity global_load_lds; LDS fragment
// reads unswizzle with pcol = kcol ^ SWZ(cn) -> conflict-free (verified: 0).
//
// Epilogue: NO LDS, NO barriers. In-register 4x4 transpose via 2-stage
// __shfl_xor butterfly within lane quads (element-tracked; R5 verified
// correct, absmax unchanged). NO launch-bounds occupancy cap: R5's (256,4)
// cap forced 4 blocks/CU and REGRESSED (57.5->64.4 us; FETCH +11% from L2
// tile thrash, deeper shared load queue behind each vmcnt(0) drain).
// Default regalloc gives ~3 blocks/CU — the measured sweet spot.
//
// MODE 1: out fp8(swz) = (acc + bias[col]) * gate[(m0>>11)*512 + col]
// MODE 2: out f32      = resid[idx] + (acc + bias[col]) * scale[col]
// MODE 3: out fp8(swz) = gelu(acc + bias[col])
// MODE 4: out f32     += (acc + bias[col]) * scale[col]   (in-place RMW)
// ---------------------------------------------------------------------------
template <int MODE>
__global__ __launch_bounds__(256) void gemm_bt(
    const unsigned char* __restrict__ A, int lda,
    const unsigned char* __restrict__ B, int ldb,
    const float* __restrict__ bias, const float* __restrict__ scale,
    const float* __restrict__ resid, void* __restrict__ outp,
    int N, int K, const float* __restrict__ gate) {
  __shared__ __align__(16) unsigned char smem[32768];
  unsigned char* As = smem;            // 128 rows x 128 B (swizzled image)
  unsigned char* Bs = smem + 16384;    // 128 rows x 128 B (swizzled image)

  const int m0 = blockIdx.x * 128, n0 = blockIdx.y * 128;
  const int tid = threadIdx.x, lane = tid & 63, w = tid >> 6;
  const int wm = w >> 1, wn = w & 1, quad = lane >> 4, cn = lane & 15;
  const int srow = lane >> 3;
  const int scol = (lane & 7) << 4;         // identity staging (m97-proven)
  const int rswz = SWZ(cn);                 // reader-side unswizzle (row&15 == cn)

  v4f acc[4][4];
  v4f zero4 = {0.f, 0.f, 0.f, 0.f};
#pragma unroll
  for (int i = 0; i < 4; i++)
#pragma unroll
    for (int j = 0; j < 4; j++) acc[i][j] = zero4;

  for (int k0 = 0; k0 < K; k0 += 128) {
    __syncthreads();
#pragma unroll
    for (int s = 0; s < 4; s++) {
      int seg = (w << 2) + s;                 // 16 segs of 8 rows x 128 B
      int row = (seg << 3) + srow;
      load16_lds(A + (size_t)(m0 + row) * lda + k0 + scol, &As[seg * 1024]);
      load16_lds(B + (size_t)(n0 + row) * ldb + k0 + scol, &Bs[seg * 1024]);
    }
    __syncthreads();
#pragma unroll
    for (int kk = 0; kk < 4; kk++) {
      long af[4], bf[4];
      int pcol = ((kk << 5) + (quad << 3)) ^ rswz;   // physical col of 8B chunk
#pragma unroll
      for (int mt = 0; mt < 4; mt++)
        af[mt] = *(const long*)&As[(wm * 64 + mt * 16 + cn) * 128 + pcol];
#pragma unroll
      for (int nt = 0; nt < 4; nt++)
        bf[nt] = *(const long*)&Bs[(wn * 64 + nt * 16 + cn) * 128 + pcol];
#pragma unroll
      for (int mt = 0; mt < 4; mt++)
#pragma unroll
        for (int nt = 0; nt < 4; nt++)
          acc[mt][nt] = __builtin_amdgcn_mfma_f32_16x16x32_fp8_fp8(af[mt], bf[nt], acc[mt][nt], 0, 0, 0);
    }
  }

  // Direct epilogue: per-fragment shuffle transpose, then store.
  const int bb = (MODE == 1) ? (m0 >> 11) : 0;
  const int p = cn & 1, q = cn & 2;
  const int erow0 = m0 + wm * 64 + quad * 4 + (cn & 3);
  const int ecol0 = n0 + wn * 64 + (cn & 12);
#pragma unroll
  for (int mt = 0; mt < 4; mt++) {
    const int row = erow0 + mt * 16;
    const int sw = SWZ(row);
#pragma unroll
    for (int nt = 0; nt < 4; nt++) {
      const int col = ecol0 + nt * 16;
      float v0 = acc[mt][nt][0], v1 = acc[mt][nt][1];
      float v2 = acc[mt][nt][2], v3 = acc[mt][nt][3];
      float s0 = p ? v0 : v1, s1 = p ? v2 : v3;
      float r0 = __shfl_xor(s0, 1), r1 = __shfl_xor(s1, 1);
      float u0 = p ? r0 : v0, u1 = p ? v1 : r0;
      float u2 = p ? r1 : v2, u3 = p ? v3 : r1;
      float t0 = q ? u0 : u2, t1 = q ? u1 : u3;
      float z0 = __shfl_xor(t0, 2), z1 = __shfl_xor(t1, 2);
      float w0 = q ? z0 : u0, w1 = q ? z1 : u1;
      float w2 = q ? u2 : z0, w3 = q ? u3 : z1;
      float4 bv = *(const float4*)&bias[col];
      w0 += bv.x; w1 += bv.y; w2 += bv.z; w3 += bv.w;
      size_t idx = (size_t)row * N + col;
      size_t sidx = (size_t)row * N + (col ^ sw);
      if (MODE == 1) {
        float4 gv = *(const float4*)&gate[bb * 512 + col];
        *(unsigned int*)((unsigned char*)outp + sidx) =
            pk_fp8x4(w0 * gv.x, w1 * gv.y, w2 * gv.z, w3 * gv.w);
      } else if (MODE == 2) {
        float4 sv = *(const float4*)&scale[col];
        float4 rv = *(const float4*)&resid[idx];
        float4 o; o.x = rv.x + w0 * sv.x; o.y = rv.y + w1 * sv.y;
        o.z = rv.z + w2 * sv.z; o.w = rv.w + w3 * sv.w;
        *(float4*)((float*)outp + idx) = o;
      } else if (MODE == 3) {
        *(unsigned int*)((unsigned char*)outp + sidx) =
            pk_fp8x4(gelu_fast(w0), gelu_fast(w1), gelu_fast(w2), gelu_fast(w3));
      } else {
        float4 sv = *(const float4*)&scale[col];
        float* op = (float*)outp + idx;
        float4 ov = *(float4*)op;
        float4 o; o.x = ov.x + w0 * sv.x; o.y = ov.y + w1 * sv.y;
        o.z = ov.z + w2 * sv.z; o.w = ov.w + w3 * sv.w;
        *(float4*)op = o;
      }
    }
  }
}

// ---------------------------------------------------------------------------
extern "C" void kernel_launch(void* const* d_in, const int* in_sizes, int n_in,
                              void* d_out, int out_size, void* d_ws, size_t ws_size,
                              hipStream_t stream) {
  (void)in_sizes; (void)n_in; (void)out_size; (void)ws_size;
  const float* x     = (const float*)d_in[0];
  const float* ln1_g = (const float*)d_in[1];
  const float* ln1_b = (const float*)d_in[2];
  const float* w3    = (const float*)d_in[3];
  const float* b3    = (const float*)d_in[4];
  const float* w5    = (const float*)d_in[5];
  const float* b5    = (const float*)d_in[6];
  const float* w7    = (const float*)d_in[7];
  const float* b7    = (const float*)d_in[8];
  const float* wmix  = (const float*)d_in[9];
  const float* bmix  = (const float*)d_in[10];
  const float* cg_w1 = (const float*)d_in[11];
  const float* cg_b1 = (const float*)d_in[12];
  const float* cg_w2 = (const float*)d_in[13];
  const float* cg_b2 = (const float*)d_in[14];
  const float* wout  = (const float*)d_in[15];
  const float* bout  = (const float*)d_in[16];
  const float* ls1   = (const float*)d_in[17];
  const float* ln2_g = (const float*)d_in[18];
  const float* ln2_b = (const float*)d_in[19];
  const float* ffn_w1= (const float*)d_in[20];
  const float* ffn_b1= (const float*)d_in[21];
  const float* ffn_w2= (const float*)d_in[22];
  const float* ffn_b2= (const float*)d_in[23];
  const float* ls2   = (const float*)d_in[24];

  char* ws = (char*)d_ws;
  unsigned char* wmix8 = (unsigned char*)(ws + 0);         // 256KB [512][512]
  unsigned char* wout8 = (unsigned char*)(ws + 262144);    // 256KB (wout^T)
  unsigned char* w18   = (unsigned char*)(ws + 524288);    // 1MB   (ffn_w1^T)
  unsigned char* w28   = (unsigned char*)(ws + 1572864);   // 1MB   (ffn_w2^T)
  float*         gsum  = (float*)(ws + 2621440);           // 32KB
  float*         gate  = (float*)(ws + 2654208);           // 32KB
  unsigned char* gbuf  = (unsigned char*)(ws + 3145728);   // 16MB fp8 g
  unsigned char* attn  = (unsigned char*)(ws + 19922944);  // 16MB fp8 attn
  unsigned char* h2buf = (unsigned char*)(ws + 36700160);  // 16MB fp8 h2
  unsigned char* tbuf  = gbuf;  // 32MB t-chunk overlays g+attn (both dead)

  // One fused pack launch: 4 weight packs + gsum zero (1310720 pairs).
  pack_all<<<1310720 / 256, 256, 0, stream>>>(wmix, wout, ffn_w1, ffn_w2,
                                              wmix8, wout8, w18, w28, gsum);

  ln1_conv<<<NB * 64, 256, 0, stream>>>(x, ln1_g, ln1_b, w3, b3, w5, b5, w7, b7, gbuf, gsum);
  gate_kernel<<<NB, 1024, 0, stream>>>(gsum, wmix, bmix, cg_w1, cg_b1, cg_w2, cg_b2, gate);

  dim3 grid_d(MTOT / 128, DIMC / 128);  // (256, 4)
  // GEMM1: attn = (g @ wmix^T + bmix) * gate  -> fp8 (swz)
  gemm_bt<1><<<grid_d, 256, 0, stream>>>(gbuf, 512, wmix8, 512,
                                         bmix, nullptr, nullptr, attn, 512, 512, gate);
  // GEMM2: y1 = x + (attn @ wout + bout) * ls1 -> d_out fp32
  gemm_bt<2><<<grid_d, 256, 0, stream>>>(attn, 512, wout8, 512,
                                         bout, ls1, x, d_out, 512, 512, nullptr);
  // LN2 -> h2 fp8 (swz)
  ln2_kernel<<<MTOT / 4, 256, 0, stream>>>((const float*)d_out, ln2_g, ln2_b, h2buf);

  // FFN in 2 M-chunks: t = gelu(h2@w1^T+b1) fp8 (swz), then d_out += (t@w2^T+b2)*ls2
  const int MC = 16384;
  for (int c = 0; c < 2; c++) {
    size_t r0 = (size_t)c * MC;
    dim3 g3(MC / 128, HID / 128);   // (128, 16)
    gemm_bt<3><<<g3, 256, 0, stream>>>(h2buf + r0 * 512, 512, w18, 512,
                                       ffn_b1, nullptr, nullptr, tbuf, HID, 512, nullptr);
    dim3 g4(MC / 128, DIMC / 128);  // (128, 4)
    gemm_bt<4><<<g4, 256, 0, stream>>>(tbuf, 2048, w28, 2048,
                                       ffn_b2, ls2, nullptr,
                                       (float*)d_out + r0 * 512, 512, 2048, nullptr);
  }
}

// Round 7
// 436.910 us; speedup vs baseline: 1.1814x; 1.1814x over previous
//
#include <hip/hip_runtime.h>
#include <hip/hip_bf16.h>
#include <stdint.h>
#include <math.h>

// DIM=512, B=16, L=2048, MLP_RATIO=4, GATE_HID=128
#define DIMC 512
#define SEQ  2048
#define NB   16
#define MTOT (NB * SEQ)          // 32768 tokens
#define HID  2048

// All fp8 GEMM-operand buffers are stored XOR-swizzled in global memory:
//   buf[row][c ^ SWZ(row)] = true[row][c]
// 8B-granule swizzle, bijective in row&15:
//   SWZ(row) = ((row&7)<<4) | (row&8)
// global_load_lds staging stays identity (raw row copy, m97-proven); the GEMM
// fragment reader unswizzles with pcol = kcol ^ SWZ(cn) (fragment rows satisfy
// row&15 == cn). Each 16-lane MFMA group hits 16 distinct 8B slots = all 32
// banks once -> ds_read_b64 conflict-free (verified: SQ_LDS_BANK_CONFLICT
// 4.19M -> 0). XOR touches bits 3-6 only: every write (2B/4B aligned) stays in
// its 8B slot, every slot stays in its 128B window.
//
// Occupancy history for gemm_bt (measured): 2 blocks/CU = 62us + 5.5x FETCH
// blowup (R6, shuffle epilogue, 140 VGPR); 3 blocks/CU = 57.5us (R3, LDS
// epilogue, 88 VGPR, FETCH ~ideal); 4 blocks/CU = 64us (R5, forced cap).
// => keep the R3 structure: LDS-transpose epilogue, no launch-bounds cap.
#define SWZ(row) ((((row) & 7) << 4) | ((row) & 8))

typedef float v4f __attribute__((ext_vector_type(4)));

__device__ __forceinline__ float bf2f(unsigned short u) {
  union { unsigned int i; float f; } v; v.i = ((unsigned int)u) << 16; return v.f;
}
__device__ __forceinline__ unsigned short f2bf(float f) {
  union { float f; unsigned int i; } v; v.f = f;
  unsigned int r = v.i + 0x7fffu + ((v.i >> 16) & 1u);  // RNE
  return (unsigned short)(r >> 16);
}
// Exact gelu (erf) — used only where output stays fp32 (gate path).
__device__ __forceinline__ float gelu_f(float v) {
  return 0.5f * v * (1.f + erff(v * 0.70710678118654752440f));
}
// Fast gelu: sigmoid form v*sigma(1.702v) — 5 VALU ops (mul,exp,add,rcp,mul).
// |err| < ~0.02 pre-quantization, absorbed by fp8 e4m3 consumers (ulp ~6%)
// and the 1e-4 layer-scales. Verified R6: absmax bit-identical (0.015625).
// Overflow-safe: exp -> 0/inf, never NaN.
__device__ __forceinline__ float gelu_fast(float v) {
  float e = __expf(v * -1.702f);
  return v * __builtin_amdgcn_rcpf(1.f + e);
}
// pack fp32 -> fp8 e4m3 (OCP)
__device__ __forceinline__ unsigned short pk_fp8(float a, float b) {
  return (unsigned short)__builtin_amdgcn_cvt_pk_fp8_f32(a, b, 0, false);
}
__device__ __forceinline__ unsigned int pk_fp8x4(float a, float b, float c, float d) {
  int lo = __builtin_amdgcn_cvt_pk_fp8_f32(a, b, 0, false);
  return (unsigned int)__builtin_amdgcn_cvt_pk_fp8_f32(c, d, lo, true);
}

typedef __attribute__((address_space(1))) const void cglobal_void;
typedef __attribute__((address_space(3))) void lds_void;
__device__ __forceinline__ void load16_lds(const void* g, void* l) {
  __builtin_amdgcn_global_load_lds((cglobal_void*)g, (lds_void*)l, 16, 0, 0);
}

// ---------------------------------------------------------------------------
// Fused weight pack: all four weights fp32 -> fp8 e4m3 (swizzled dest) in one
// launch; also zeroes gsum. Pair index p covers: [0,131072) wmix;
// [131072,262144) wout^T; [262144,786432) ffn_w1^T; [786432,1310720) ffn_w2^T.
// ---------------------------------------------------------------------------
__global__ __launch_bounds__(256) void pack_all(
    const float* __restrict__ wmix, const float* __restrict__ wout,
    const float* __restrict__ ffn_w1, const float* __restrict__ ffn_w2,
    unsigned char* __restrict__ wmix8, unsigned char* __restrict__ wout8,
    unsigned char* __restrict__ w18, unsigned char* __restrict__ w28,
    float* __restrict__ gsum) {
  int p = blockIdx.x * 256 + threadIdx.x;
  if (p < NB * DIMC) gsum[p] = 0.f;

  const float* in; unsigned char* out; int R, C, trans;
  if (p < 131072)      { in = wmix;   out = wmix8; R = 512;  C = 512;  trans = 0; }
  else if (p < 262144) { in = wout;   out = wout8; R = 512;  C = 512;  trans = 1; p -= 131072; }
  else if (p < 786432) { in = ffn_w1; out = w18;   R = 2048; C = 512;  trans = 1; p -= 262144; }
  else                 { in = ffn_w2; out = w28;   R = 512;  C = 2048; trans = 1; p -= 786432; }
  int r = (p * 2) / C, c = (p * 2) - r * C;
  float v0, v1;
  if (trans) { v0 = in[(size_t)c * R + r]; v1 = in[(size_t)(c + 1) * R + r]; }
  else       { v0 = in[(size_t)r * C + c]; v1 = in[(size_t)r * C + c + 1]; }
  *(unsigned short*)(out + (size_t)r * C + (c ^ SWZ(r))) = pk_fp8(v0, v1);
}

// ---------------------------------------------------------------------------
// LN1 + (dwconv3+5+7)/3 + GELU -> g fp8 [M,512] (swizzled); accumulates gsum.
// ---------------------------------------------------------------------------
__global__ __launch_bounds__(256) void ln1_conv(
    const float* __restrict__ x, const float* __restrict__ lg, const float* __restrict__ lb,
    const float* __restrict__ w3, const float* __restrict__ b3,
    const float* __restrict__ w5, const float* __restrict__ b5,
    const float* __restrict__ w7, const float* __restrict__ b7,
    unsigned char* __restrict__ gout, float* __restrict__ gsum) {
  __shared__ __align__(16) unsigned short ht[38 * DIMC];
  int blk = blockIdx.x;
  int b = blk >> 6;
  int l0 = (blk & 63) << 5;
  int tid = threadIdx.x, lane = tid & 63, w = tid >> 6;

  for (int r = w; r < 38; r += 4) {
    int l = l0 - 3 + r;
    unsigned short* hrow = ht + r * DIMC;
    if (l < 0 || l >= SEQ) {
      ushort4 z; z.x = z.y = z.z = z.w = 0;
      *(ushort4*)&hrow[lane * 4] = z;
      *(ushort4*)&hrow[256 + lane * 4] = z;
    } else {
      const float4* xp = (const float4*)(x + ((size_t)(b * SEQ + l)) * DIMC);
      float4 v0 = xp[lane], v1 = xp[lane + 64];
      float s = v0.x + v0.y + v0.z + v0.w + v1.x + v1.y + v1.z + v1.w;
      float q = v0.x * v0.x + v0.y * v0.y + v0.z * v0.z + v0.w * v0.w +
                v1.x * v1.x + v1.y * v1.y + v1.z * v1.z + v1.w * v1.w;
#pragma unroll
      for (int o = 32; o > 0; o >>= 1) { s += __shfl_xor(s, o); q += __shfl_xor(q, o); }
      float mu = s * (1.f / 512.f);
      float rs = rsqrtf(q * (1.f / 512.f) - mu * mu + 1e-5f);
      float4 ga = ((const float4*)lg)[lane], gb = ((const float4*)lg)[lane + 64];
      float4 ba = ((const float4*)lb)[lane], bb = ((const float4*)lb)[lane + 64];
      ushort4 o0, o1;
      o0.x = f2bf((v0.x - mu) * rs * ga.x + ba.x);
      o0.y = f2bf((v0.y - mu) * rs * ga.y + ba.y);
      o0.z = f2bf((v0.z - mu) * rs * ga.z + ba.z);
      o0.w = f2bf((v0.w - mu) * rs * ga.w + ba.w);
      o1.x = f2bf((v1.x - mu) * rs * gb.x + bb.x);
      o1.y = f2bf((v1.y - mu) * rs * gb.y + bb.y);
      o1.z = f2bf((v1.z - mu) * rs * gb.z + bb.z);
      o1.w = f2bf((v1.w - mu) * rs * gb.w + bb.w);
      *(ushort4*)&hrow[lane * 4] = o0;
      *(ushort4*)&hrow[256 + lane * 4] = o1;
    }
  }
  __syncthreads();

  int d0 = tid << 1;
  float t3[2][3], t5[2][5], t7[2][7], cb[2];
#pragma unroll
  for (int j = 0; j < 2; j++) {
    int d = d0 + j;
    cb[j] = b3[d] + b5[d] + b7[d];
#pragma unroll
    for (int t = 0; t < 3; t++) t3[j][t] = w3[d * 3 + t];
#pragma unroll
    for (int t = 0; t < 5; t++) t5[j][t] = w5[d * 5 + t];
#pragma unroll
    for (int t = 0; t < 7; t++) t7[j][t] = w7[d * 7 + t];
  }
  float sum0 = 0.f, sum1 = 0.f;
  size_t rbase = ((size_t)(b * SEQ + l0)) * DIMC;
  for (int l = 0; l < 32; l++) {
    float h0[7], h1[7];
#pragma unroll
    for (int r = 0; r < 7; r++) {
      unsigned int pk = *(const unsigned int*)&ht[(l + r) * DIMC + d0];
      h0[r] = bf2f((unsigned short)pk);
      h1[r] = bf2f((unsigned short)(pk >> 16));
    }
    float a0 = cb[0], a1 = cb[1];
#pragma unroll
    for (int t = 0; t < 7; t++) { a0 += t7[0][t] * h0[t];     a1 += t7[1][t] * h1[t]; }
#pragma unroll
    for (int t = 0; t < 5; t++) { a0 += t5[0][t] * h0[t + 1]; a1 += t5[1][t] * h1[t + 1]; }
#pragma unroll
    for (int t = 0; t < 3; t++) { a0 += t3[0][t] * h0[t + 2]; a1 += t3[1][t] * h1[t + 2]; }
    a0 *= (1.f / 3.f); a1 *= (1.f / 3.f);
    float g0 = gelu_fast(a0), g1 = gelu_fast(a1);
    // row = b*SEQ + l0 + l; row&15 == l&15 (l0 multiple of 32)
    *(unsigned short*)(gout + rbase + (size_t)l * DIMC + (d0 ^ SWZ(l))) = pk_fp8(g0, g1);
    sum0 += g0; sum1 += g1;
  }
  atomicAdd(&gsum[b * DIMC + d0], sum0);
  atomicAdd(&gsum[b * DIMC + d0 + 1], sum1);
}

// ---------------------------------------------------------------------------
// Gate (exact fp32): ct = (gsum/L)@wmix^T + bmix; gate = sig(gelu(ct@w1+b1)@w2+b2)
// ---------------------------------------------------------------------------
__global__ __launch_bounds__(1024) void gate_kernel(
    const float* __restrict__ gsum, const float* __restrict__ wmix, const float* __restrict__ bmix,
    const float* __restrict__ cg_w1, const float* __restrict__ cg_b1,
    const float* __restrict__ cg_w2, const float* __restrict__ cg_b2,
    float* __restrict__ gate) {
  __shared__ float gbar[512];
  __shared__ float ct[512];
  __shared__ float part2[8][128];
  __shared__ float t1[128];
  __shared__ float part3[2][512];
  int b = blockIdx.x, tid = threadIdx.x;
  int lane = tid & 63, w = tid >> 6;   // 16 waves

  if (tid < 512) gbar[tid] = gsum[b * 512 + tid] * (1.f / (float)SEQ);
  __syncthreads();

  // Phase 1: ct[o] = gbar . wmix[o,:] + bmix[o].
  {
    const float4* gb4 = (const float4*)gbar;
    float4 g0 = gb4[lane * 2], g1 = gb4[lane * 2 + 1];
#pragma unroll 4
    for (int i = 0; i < 32; i++) {
      int o = w * 32 + i;
      const float4* wr = (const float4*)(wmix + (size_t)o * 512);
      float4 a0 = wr[lane * 2], a1 = wr[lane * 2 + 1];
      float s = a0.x * g0.x + a0.y * g0.y + a0.z * g0.z + a0.w * g0.w +
                a1.x * g1.x + a1.y * g1.y + a1.z * g1.z + a1.w * g1.w;
#pragma unroll
      for (int off = 32; off > 0; off >>= 1) s += __shfl_xor(s, off);
      if (lane == 0) ct[o] = s + bmix[o];
    }
  }
  __syncthreads();

  // Phase 2: t1[h] = gelu(ct . cg_w1[:,h] + cg_b1[h]).
  {
    int h = tid & 127, g = tid >> 7;
    float s = 0.f;
    const float* wp = cg_w1 + (size_t)(g * 64) * 128 + h;
#pragma unroll 8
    for (int c = 0; c < 64; c++) s += ct[g * 64 + c] * wp[c * 128];
    part2[g][h] = s;
  }
  __syncthreads();
  if (tid < 128) {
    float s = cg_b1[tid];
#pragma unroll
    for (int g = 0; g < 8; g++) s += part2[g][tid];
    t1[tid] = gelu_f(s);
  }
  __syncthreads();

  // Phase 3: gate[o] = sigmoid(t1 . cg_w2[:,o] + cg_b2[o]).
  {
    int o = tid & 511, g = tid >> 9;
    float s = 0.f;
    const float* wp = cg_w2 + (size_t)(g * 64) * 512 + o;
#pragma unroll 8
    for (int h = 0; h < 64; h++) s += t1[g * 64 + h] * wp[h * 512];
    part3[g][o] = s;
  }
  __syncthreads();
  if (tid < 512) {
    float s = cg_b2[tid] + part3[0][tid] + part3[1][tid];
    gate[b * 512 + tid] = 1.f / (1.f + expf(-s));
  }
}

// ---------------------------------------------------------------------------
// LN2: h2 = LN(y) fp8 (swizzled). One wave per token.
// ---------------------------------------------------------------------------
__global__ __launch_bounds__(256) void ln2_kernel(
    const float* __restrict__ y, const float* __restrict__ lg, const float* __restrict__ lb,
    unsigned char* __restrict__ h2) {
  int tok = (blockIdx.x << 2) + (threadIdx.x >> 6);
  int lane = threadIdx.x & 63;
  const float4* yp = (const float4*)(y + ((size_t)tok) * DIMC);
  float4 v0 = yp[lane], v1 = yp[lane + 64];
  float s = v0.x + v0.y + v0.z + v0.w + v1.x + v1.y + v1.z + v1.w;
  float q = v0.x * v0.x + v0.y * v0.y + v0.z * v0.z + v0.w * v0.w +
            v1.x * v1.x + v1.y * v1.y + v1.z * v1.z + v1.w * v1.w;
#pragma unroll
  for (int o = 32; o > 0; o >>= 1) { s += __shfl_xor(s, o); q += __shfl_xor(q, o); }
  float mu = s * (1.f / 512.f);
  float rs = rsqrtf(q * (1.f / 512.f) - mu * mu + 1e-5f);
  float4 ga = ((const float4*)lg)[lane], gb = ((const float4*)lg)[lane + 64];
  float4 ba = ((const float4*)lb)[lane], bb = ((const float4*)lb)[lane + 64];
  unsigned char* hp = h2 + (size_t)tok * DIMC;
  int sw = SWZ(tok);
  *(unsigned int*)(hp + ((lane * 4) ^ sw)) = pk_fp8x4(
      (v0.x - mu) * rs * ga.x + ba.x, (v0.y - mu) * rs * ga.y + ba.y,
      (v0.z - mu) * rs * ga.z + ba.z, (v0.w - mu) * rs * ga.w + ba.w);
  *(unsigned int*)(hp + (256 + ((lane * 4) ^ sw))) = pk_fp8x4(
      (v1.x - mu) * rs * gb.x + bb.x, (v1.y - mu) * rs * gb.y + bb.y,
      (v1.z - mu) * rs * gb.z + bb.z, (v1.w - mu) * rs * gb.w + bb.w);
}

// ---------------------------------------------------------------------------
// fp8 GEMM, C = A @ B^T (+epilogue). A [M,lda], B [N,ldb] fp8, K-major,
// both stored XOR-swizzled (SWZ). 128x128 tile, BK=128, 4 waves x 4x4
// mfma_f32_16x16x32_fp8_fp8. Staging = identity global_load_lds; LDS fragment
// reads unswizzle with pcol = kcol ^ SWZ(cn) -> conflict-free (verified: 0).
// Epilogue ebuf is XOR-swizzled (col ^ (row&4)<<2 floats): transpose writes
// spread over all 32 banks. R3 structure (88 VGPR, 3 blocks/CU) — measured
// best vs shuffle-epilogue variants (see SWZ comment above).
// MODE 1: out fp8(swz) = (acc + bias[col]) * gate[(m0>>11)*512 + col]
// MODE 2: out f32      = resid[idx] + (acc + bias[col]) * scale[col]
// MODE 3: out fp8(swz) = gelu(acc + bias[col])
// MODE 4: out f32     += (acc + bias[col]) * scale[col]   (in-place RMW)
// ---------------------------------------------------------------------------
template <int MODE>
__global__ __launch_bounds__(256) void gemm_bt(
    const unsigned char* __restrict__ A, int lda,
    const unsigned char* __restrict__ B, int ldb,
    const float* __restrict__ bias, const float* __restrict__ scale,
    const float* __restrict__ resid, void* __restrict__ outp,
    int N, int K, const float* __restrict__ gate) {
  __shared__ __align__(16) unsigned char smem[32768];
  unsigned char* As = smem;            // 128 rows x 128 B (swizzled image)
  unsigned char* Bs = smem + 16384;    // 128 rows x 128 B (swizzled image)
  float* ebuf = (float*)smem;          // epilogue: 64 x 128 fp32 (XOR-swizzled)

  const int m0 = blockIdx.x * 128, n0 = blockIdx.y * 128;
  const int tid = threadIdx.x, lane = tid & 63, w = tid >> 6;
  const int wm = w >> 1, wn = w & 1, quad = lane >> 4, cn = lane & 15;
  const int srow = lane >> 3;
  const int scol = (lane & 7) << 4;         // identity staging (m97-proven)
  const int rswz = SWZ(cn);                 // reader-side unswizzle (row&15 == cn)

  v4f acc[4][4];
  v4f zero4 = {0.f, 0.f, 0.f, 0.f};
#pragma unroll
  for (int i = 0; i < 4; i++)
#pragma unroll
    for (int j = 0; j < 4; j++) acc[i][j] = zero4;

  for (int k0 = 0; k0 < K; k0 += 128) {
    __syncthreads();
#pragma unroll
    for (int s = 0; s < 4; s++) {
      int seg = (w << 2) + s;                 // 16 segs of 8 rows x 128 B
      int row = (seg << 3) + srow;
      load16_lds(A + (size_t)(m0 + row) * lda + k0 + scol, &As[seg * 1024]);
      load16_lds(B + (size_t)(n0 + row) * ldb + k0 + scol, &Bs[seg * 1024]);
    }
    __syncthreads();
#pragma unroll
    for (int kk = 0; kk < 4; kk++) {
      long af[4], bf[4];
      int pcol = ((kk << 5) + (quad << 3)) ^ rswz;   // physical col of 8B chunk
#pragma unroll
      for (int mt = 0; mt < 4; mt++)
        af[mt] = *(const long*)&As[(wm * 64 + mt * 16 + cn) * 128 + pcol];
#pragma unroll
      for (int nt = 0; nt < 4; nt++)
        bf[nt] = *(const long*)&Bs[(wn * 64 + nt * 16 + cn) * 128 + pcol];
#pragma unroll
      for (int mt = 0; mt < 4; mt++)
#pragma unroll
        for (int nt = 0; nt < 4; nt++)
          acc[mt][nt] = __builtin_amdgcn_mfma_f32_16x16x32_fp8_fp8(af[mt], bf[nt], acc[mt][nt], 0, 0, 0);
    }
  }

  // Epilogue via LDS transpose, two 64-row halves. ebuf XOR-swizzle:
  // element (row,col) lives at col ^ ((row&4)<<2) -> writes are 2-way (free),
  // reads stay contiguous float4 (XOR only flips bit4 of the float index).
  const int bb = (MODE == 1) ? (m0 >> 11) : 0;
#pragma unroll
  for (int h = 0; h < 2; h++) {
    __syncthreads();
    if (wm == h) {
      const int exsw = (quad & 1) << 4;   // == (row&4)<<2 since row=mt*16+quad*4+r
#pragma unroll
      for (int mt = 0; mt < 4; mt++)
#pragma unroll
        for (int nt = 0; nt < 4; nt++)
#pragma unroll
          for (int r = 0; r < 4; r++)
            ebuf[(mt * 16 + quad * 4 + r) * 128 + ((wn * 64 + nt * 16 + cn) ^ exsw)] = acc[mt][nt][r];
    }
    __syncthreads();
#pragma unroll
    for (int i = 0; i < 8; i++) {
      int fi = (i << 8) + tid;            // 0..2047 float4 index
      int r = fi >> 5, c4 = fi & 31;
      int row = m0 + (h << 6) + r;
      int col = n0 + (c4 << 2);
      const float* e = &ebuf[(fi << 2) ^ ((r & 4) << 2)];
      float v0 = e[0], v1 = e[1], v2 = e[2], v3 = e[3];
      float4 bv = *(const float4*)&bias[col];
      v0 += bv.x; v1 += bv.y; v2 += bv.z; v3 += bv.w;
      size_t idx = (size_t)row * N + col;
      // fp8 outputs are stored swizzled (they feed the next GEMM's A operand)
      size_t sidx = (size_t)row * N + (col ^ SWZ(row));
      if (MODE == 1) {
        float4 gv = *(const float4*)&gate[bb * 512 + col];
        *(unsigned int*)((unsigned char*)outp + sidx) =
            pk_fp8x4(v0 * gv.x, v1 * gv.y, v2 * gv.z, v3 * gv.w);
      } else if (MODE == 2) {
        float4 sv = *(const float4*)&scale[col];
        float4 rv = *(const float4*)&resid[idx];
        float4 o; o.x = rv.x + v0 * sv.x; o.y = rv.y + v1 * sv.y;
        o.z = rv.z + v2 * sv.z; o.w = rv.w + v3 * sv.w;
        *(float4*)((float*)outp + idx) = o;
      } else if (MODE == 3) {
        *(unsigned int*)((unsigned char*)outp + sidx) =
            pk_fp8x4(gelu_fast(v0), gelu_fast(v1), gelu_fast(v2), gelu_fast(v3));
      } else {
        float4 sv = *(const float4*)&scale[col];
        float* op = (float*)outp + idx;
        float4 ov = *(float4*)op;
        float4 o; o.x = ov.x + v0 * sv.x; o.y = ov.y + v1 * sv.y;
        o.z = ov.z + v2 * sv.z; o.w = ov.w + v3 * sv.w;
        *(float4*)op = o;
      }
    }
  }
}

// ---------------------------------------------------------------------------
extern "C" void kernel_launch(void* const* d_in, const int* in_sizes, int n_in,
                              void* d_out, int out_size, void* d_ws, size_t ws_size,
                              hipStream_t stream) {
  (void)in_sizes; (void)n_in; (void)out_size; (void)ws_size;
  const float* x     = (const float*)d_in[0];
  const float* ln1_g = (const float*)d_in[1];
  const float* ln1_b = (const float*)d_in[2];
  const float* w3    = (const float*)d_in[3];
  const float* b3    = (const float*)d_in[4];
  const float* w5    = (const float*)d_in[5];
  const float* b5    = (const float*)d_in[6];
  const float* w7    = (const float*)d_in[7];
  const float* b7    = (const float*)d_in[8];
  const float* wmix  = (const float*)d_in[9];
  const float* bmix  = (const float*)d_in[10];
  const float* cg_w1 = (const float*)d_in[11];
  const float* cg_b1 = (const float*)d_in[12];
  const float* cg_w2 = (const float*)d_in[13];
  const float* cg_b2 = (const float*)d_in[14];
  const float* wout  = (const float*)d_in[15];
  const float* bout  = (const float*)d_in[16];
  const float* ls1   = (const float*)d_in[17];
  const float* ln2_g = (const float*)d_in[18];
  const float* ln2_b = (const float*)d_in[19];
  const float* ffn_w1= (const float*)d_in[20];
  const float* ffn_b1= (const float*)d_in[21];
  const float* ffn_w2= (const float*)d_in[22];
  const float* ffn_b2= (const float*)d_in[23];
  const float* ls2   = (const float*)d_in[24];

  char* ws = (char*)d_ws;
  unsigned char* wmix8 = (unsigned char*)(ws + 0);         // 256KB [512][512]
  unsigned char* wout8 = (unsigned char*)(ws + 262144);    // 256KB (wout^T)
  unsigned char* w18   = (unsigned char*)(ws + 524288);    // 1MB   (ffn_w1^T)
  unsigned char* w28   = (unsigned char*)(ws + 1572864);   // 1MB   (ffn_w2^T)
  float*         gsum  = (float*)(ws + 2621440);           // 32KB
  float*         gate  = (float*)(ws + 2654208);           // 32KB
  unsigned char* gbuf  = (unsigned char*)(ws + 3145728);   // 16MB fp8 g
  unsigned char* attn  = (unsigned char*)(ws + 19922944);  // 16MB fp8 attn
  unsigned char* h2buf = (unsigned char*)(ws + 36700160);  // 16MB fp8 h2
  unsigned char* tbuf  = gbuf;  // 32MB t-chunk overlays g+attn (both dead)

  // One fused pack launch: 4 weight packs + gsum zero (1310720 pairs).
  pack_all<<<1310720 / 256, 256, 0, stream>>>(wmix, wout, ffn_w1, ffn_w2,
                                              wmix8, wout8, w18, w28, gsum);

  ln1_conv<<<NB * 64, 256, 0, stream>>>(x, ln1_g, ln1_b, w3, b3, w5, b5, w7, b7, gbuf, gsum);
  gate_kernel<<<NB, 1024, 0, stream>>>(gsum, wmix, bmix, cg_w1, cg_b1, cg_w2, cg_b2, gate);

  dim3 grid_d(MTOT / 128, DIMC / 128);  // (256, 4)
  // GEMM1: attn = (g @ wmix^T + bmix) * gate  -> fp8 (swz)
  gemm_bt<1><<<grid_d, 256, 0, stream>>>(gbuf, 512, wmix8, 512,
                                         bmix, nullptr, nullptr, attn, 512, 512, gate);
  // GEMM2: y1 = x + (attn @ wout + bout) * ls1 -> d_out fp32
  gemm_bt<2><<<grid_d, 256, 0, stream>>>(attn, 512, wout8, 512,
                                         bout, ls1, x, d_out, 512, 512, nullptr);
  // LN2 -> h2 fp8 (swz)
  ln2_kernel<<<MTOT / 4, 256, 0, stream>>>((const float*)d_out, ln2_g, ln2_b, h2buf);

  // FFN in 2 M-chunks: t = gelu(h2@w1^T+b1) fp8 (swz), then d_out += (t@w2^T+b2)*ls2
  const int MC = 16384;
  for (int c = 0; c < 2; c++) {
    size_t r0 = (size_t)c * MC;
    dim3 g3(MC / 128, HID / 128);   // (128, 16)
    gemm_bt<3><<<g3, 256, 0, stream>>>(h2buf + r0 * 512, 512, w18, 512,
                                       ffn_b1, nullptr, nullptr, tbuf, HID, 512, nullptr);
    dim3 g4(MC / 128, DIMC / 128);  // (128, 4)
    gemm_bt<4><<<g4, 256, 0, stream>>>(tbuf, 2048, w28, 2048,
                                       ffn_b2, ls2, nullptr,
                                       (float*)d_out + r0 * 512, 512, 2048, nullptr);
  }
}